// Round 8
// baseline (245.071 us; speedup 1.0000x reference)
//
#include <hip/hip_runtime.h>
#include <hip/hip_bf16.h>

typedef unsigned short u16;
typedef short short8 __attribute__((ext_vector_type(8)));
typedef float floatx4 __attribute__((ext_vector_type(4)));
typedef __fp16 half2v __attribute__((ext_vector_type(2)));
typedef __fp16 half4v __attribute__((ext_vector_type(4)));

#define MFMA16(a, b, c) __builtin_amdgcn_mfma_f32_16x16x32_bf16((a), (b), (c), 0, 0, 0)
#define MFMA_PV(a, b, c) __builtin_amdgcn_mfma_f32_16x16x16f16((a), (b), (c), 0, 0, 0)

union U128u { uint4 q; u16 s[8]; };
union H4u { half4v h4; half2v h2[2]; unsigned u[2]; };

__device__ __forceinline__ u16 f2bf(float f) {
  union { float f; unsigned u; } v; v.f = f;
  unsigned r = v.u + 0x7fffu + ((v.u >> 16) & 1u);
  return (u16)(r >> 16);
}

__device__ __forceinline__ float bf2f(u16 s) {
  union { unsigned u; float f; } v; v.u = ((unsigned)s) << 16;
  return v.f;
}

__device__ __forceinline__ float fexp2(float x) {
#if __has_builtin(__builtin_amdgcn_exp2f)
  return __builtin_amdgcn_exp2f(x);
#else
  return exp2f(x);
#endif
}

// async global->LDS, 16B per lane. lds pointer must be wave-uniform. (GEMMs only.)
__device__ __forceinline__ void async16(const u16* g, u16* l) {
  __builtin_amdgcn_global_load_lds(
      (const __attribute__((address_space(1))) unsigned int*)g,
      (__attribute__((address_space(3))) unsigned int*)l, 16, 0, 0);
}

// ---------------- merged prep: cast x, cast Wo, repack Wqkv + biases ----------------

__global__ __launch_bounds__(256) void prep_all(
    const float* __restrict__ x, const float* __restrict__ Wo,
    const float* __restrict__ Wq, const float* __restrict__ bq,
    const float* __restrict__ Wk, const float* __restrict__ bk,
    const float* __restrict__ Wv, const float* __restrict__ bv,
    u16* __restrict__ Xb, u16* __restrict__ Wob,
    u16* __restrict__ Wt, float* __restrict__ ball) {
  int bid = blockIdx.x;
  int tid = threadIdx.x;
  if (bid < 5120) {
    // cast: blocks [0,4096) -> x (1048576 float4), [4096,5120) -> Wo (262144 float4)
    const float* src = bid < 4096 ? x : Wo;
    u16* dst = bid < 4096 ? Xb : Wob;
    int i = (bid < 4096 ? bid : bid - 4096) * 256 + tid;
    float4 v = ((const float4*)src)[i];
    union { unsigned long long ll; u16 s[4]; } o;
    o.s[0] = f2bf(v.x); o.s[1] = f2bf(v.y); o.s[2] = f2bf(v.z); o.s[3] = f2bf(v.w);
    ((unsigned long long*)dst)[i] = o.ll;
    return;
  }
  int id = (bid - 5120) * 256 + tid;  // 786432 total
  int kk4 = id & 15;
  int d = (id >> 4) & 1023;
  int h = (id >> 14) & 15;
  int wsel = id >> 18;
  const float* W = wsel == 0 ? Wq : (wsel == 1 ? Wk : Wv);
  float4 v = *(const float4*)(W + ((size_t)(h * 1024 + d)) * 64 + kk4 * 4);
  int nb = wsel * 1024 + h * 64 + kk4 * 4;
  Wt[(size_t)(nb + 0) * 1024 + d] = f2bf(v.x);
  Wt[(size_t)(nb + 1) * 1024 + d] = f2bf(v.y);
  Wt[(size_t)(nb + 2) * 1024 + d] = f2bf(v.z);
  Wt[(size_t)(nb + 3) * 1024 + d] = f2bf(v.w);
  if (id < 3072) {
    int ws2 = id >> 10, hk = id & 1023;
    const float* bsrc = ws2 == 0 ? bq : (ws2 == 1 ? bk : bv);
    ball[id] = bsrc[hk];
  }
}

// VtF[bh][chunk(128)][kq(4)][d(64)][k(4)] f16 <- QKV V-part (bf16->f16 exact).
// chunk = 16 seq positions; PV B-fragment = half4 at (kq=l4, d, k0..3), 8B coalesced.
__global__ __launch_bounds__(256) void transpose_v(const u16* __restrict__ QKV,
                                                   u16* __restrict__ VtF) {
  __shared__ u16 t[64][65];
  int tid = threadIdx.x;
  int bh = blockIdx.y, b = bh >> 4, h = bh & 15;
  int s0 = blockIdx.x * 64;          // 64 seq rows per block
  int v0 = blockIdx.x * 4;           // 4 chunks per block
  {
    int r = tid >> 2, c0 = (tid & 3) * 16;
    const u16* src = QKV + (size_t)(b * 2048 + s0 + r) * 3072 + 2048 + h * 64 + c0;
    U128u a, c;
    a.q = *(const uint4*)src;
    c.q = *(const uint4*)(src + 8);
#pragma unroll
    for (int j = 0; j < 8; ++j) { t[r][c0 + j] = a.s[j]; t[r][c0 + 8 + j] = c.s[j]; }
  }
  __syncthreads();
  {
    int d = tid & 63, vloc = tid >> 6;  // 4 chunks x 64 d
    int sl = vloc * 16;
    u16* dst = VtF + ((size_t)(bh * 128 + v0 + vloc)) * 1024 + d * 4;
#pragma unroll
    for (int kq = 0; kq < 4; ++kq) {
      float f0 = bf2f(t[sl + kq * 4 + 0][d]);
      float f1 = bf2f(t[sl + kq * 4 + 1][d]);
      float f2 = bf2f(t[sl + kq * 4 + 2][d]);
      float f3 = bf2f(t[sl + kq * 4 + 3][d]);
      union { half2v h2[2]; uint2 u2; } o;
      o.h2[0] = __builtin_amdgcn_cvt_pkrtz(f0, f1);
      o.h2[1] = __builtin_amdgcn_cvt_pkrtz(f2, f3);
      *(uint2*)(dst + kq * 256) = o.u2;
    }
  }
}

// ---------------- GEMM: C[M,N] = A[M,K] * B^T (B stored [N,K]) + bias, opt scale ----------------
// 1-D grid, XCD-swizzled: xcd owns bm cluster of 4 (keeps A-tiles in per-XCD L2).

__device__ __forceinline__ void store_out(u16* p, float v) { *p = f2bf(v); }
__device__ __forceinline__ void store_out(float* p, float v) { *p = v; }

template <int BN, typename OutT>
__global__ __launch_bounds__(256) void gemm_bt(
    const u16* __restrict__ A, const u16* __restrict__ B,
    const float* __restrict__ bias, OutT* __restrict__ C,
    int M, int N, int K, int scaleNend, float scaleVal) {
  constexpr int TN = BN / 32;  // n-tiles per wave
  __shared__ __attribute__((aligned(16))) u16 As[128 * 32];
  __shared__ __attribute__((aligned(16))) u16 Bs[BN * 32];
  const int tid = threadIdx.x;
  const int w = tid >> 6, lane = tid & 63;
  const int l15 = lane & 15, l4 = lane >> 4;
  const int lin = blockIdx.x;
  const int xcd = lin & 7, sblk = lin >> 3;
  const int bm = xcd * 4 + (sblk & 3);   // M=4096 -> 32 bm tiles, 4 per XCD
  const int bn = sblk >> 2;
  const int wm = (w & 1) * 64, wn = (w >> 1) * (BN / 2);

  floatx4 acc[4][TN];
#pragma unroll
  for (int i = 0; i < 4; ++i)
#pragma unroll
    for (int j = 0; j < TN; ++j) acc[i][j] = (floatx4){0.f, 0.f, 0.f, 0.f};

  for (int k0 = 0; k0 < K; k0 += 32) {
    __syncthreads();
#pragma unroll
    for (int j = 0; j < 2; ++j) {
      int i = j * 256 + tid;
      int row = i >> 2, ko = (i & 3) * 8;
      async16(A + (size_t)(bm * 128 + row) * K + k0 + ko, As + (j * 256 + w * 64) * 8);
    }
#pragma unroll
    for (int j = 0; j < BN / 64; ++j) {
      int i = j * 256 + tid;
      int row = i >> 2, ko = (i & 3) * 8;
      async16(B + (size_t)(bn * BN + row) * K + k0 + ko, Bs + (j * 256 + w * 64) * 8);
    }
    __syncthreads();
    short8 af[4], bf[TN];
#pragma unroll
    for (int t = 0; t < 4; ++t)
      af[t] = *(const short8*)(As + (wm + t * 16 + l15) * 32 + l4 * 8);
#pragma unroll
    for (int t = 0; t < TN; ++t)
      bf[t] = *(const short8*)(Bs + (wn + t * 16 + l15) * 32 + l4 * 8);
#pragma unroll
    for (int tm = 0; tm < 4; ++tm)
#pragma unroll
      for (int tn = 0; tn < TN; ++tn) acc[tm][tn] = MFMA16(af[tm], bf[tn], acc[tm][tn]);
  }

#pragma unroll
  for (int tn = 0; tn < TN; ++tn) {
    int col = bn * BN + wn + tn * 16 + l15;
    float bv = bias[col];
    float sc = (col < scaleNend) ? scaleVal : 1.0f;
#pragma unroll
    for (int tm = 0; tm < 4; ++tm) {
      int row0 = bm * 128 + wm + tm * 16 + l4 * 4;
#pragma unroll
      for (int r = 0; r < 4; ++r) {
        float v = (acc[tm][tn][r] + bv) * sc;
        store_out(C + (size_t)(row0 + r) * N + col, v);
      }
    }
  }
}

// ---------------- attention (fully in-register P; no LDS/barriers in K-loop) ----------------
// S^T output C-layout (col=q=lane&15, row=key=(lane>>4)*4+r) IS the A-operand layout of
// v_mfma_f32_16x16x16_f16 (m=lane&15, k=(lane>>4)*4+i) with m=q,k=key -- so P goes
// MFMA -> exp -> cvt_pkrtz -> MFMA without ever touching LDS or crossing lanes.
// Block: 64 q-rows of one (b,h); wave w: q-half (w>>1, 32 rows, tq=2) x key-half (w&1,
// 1024 keys, 32 supersteps of 32). Oacc = 32 AGPR (tq=2) -> ~105 total regs -> 4 waves/SIMD.
// K frags register-direct from L2 (XCD swizzle keeps K/V L2-resident, r3: FETCH 12.5MB).
// V pre-converted bf16->f16 (exact). Q pre-scaled log2(e)/8 -> raw exp2; unnormalized
// accumulate (flat softmax, max-free safe); per-wave partials combined once in LDS.

__global__ __launch_bounds__(256, 4) void attn_kernel(const u16* __restrict__ QKV,
                                                      const u16* __restrict__ VtF,
                                                      u16* __restrict__ Ob) {
  __shared__ __attribute__((aligned(16))) u16 lds[4 * 2368];  // per-wave Osum[32][72]bf16 + l[32]f32
  const int tid = threadIdx.x;
  const int w = tid >> 6, lane = tid & 63;
  const int l15 = lane & 15, l4 = lane >> 4;
  const int lin = blockIdx.x;                 // 1024 blocks
  const int xcd = lin & 7, sblk = lin >> 3;   // sblk in [0,128)
  const int bh = xcd * 4 + (sblk & 3);        // 4 bh per XCD
  const int q0 = (sblk >> 2) * 64;            // 32 q-tiles of 64
  const int b = bh >> 4, h = bh & 15;
  const int qh = w >> 1, kh = w & 1;

  // Q fragments (B-operand of S^T): rows q0 + qh*32 + tq*16 + l15
  short8 qf[2][2];
  {
    const u16* Qb = QKV + (size_t)(b * 2048 + q0 + qh * 32) * 3072 + h * 64;
#pragma unroll
    for (int tq = 0; tq < 2; ++tq)
#pragma unroll
      for (int s = 0; s < 2; ++s)
        qf[tq][s] = *(const short8*)(Qb + (size_t)(tq * 16 + l15) * 3072 + s * 32 + l4 * 8);
  }

  floatx4 Oacc[2][4];
#pragma unroll
  for (int i = 0; i < 2; ++i)
#pragma unroll
    for (int j = 0; j < 4; ++j) Oacc[i][j] = (floatx4){0.f, 0.f, 0.f, 0.f};
  float lpart[2] = {0.f, 0.f};

  const u16* const Kb = QKV + (size_t)(b * 2048 + kh * 1024) * 3072 + 1024 + h * 64;
  const __fp16* const Vw =
      (const __fp16*)VtF + ((size_t)(bh * 128 + kh * 64)) * 1024;  // chunk stride 1024 f16

  for (int c = 0; c < 32; ++c) {  // 32-key supersteps
    const int kb0 = c * 32;
    // K fragments (A-operand of S^T): key = kb0 + t*16 + l15, d = s*32 + l4*8
    short8 kf[2][2];
#pragma unroll
    for (int t = 0; t < 2; ++t)
#pragma unroll
      for (int s = 0; s < 2; ++s)
        kf[t][s] = *(const short8*)(Kb + (size_t)(kb0 + t * 16 + l15) * 3072 + s * 32 + l4 * 8);
    // V fragments (B-operand of PV, f16): d = td*16+l15, keys l4*4..+3 of 16-key chunk
    half4v vf[2][4];
#pragma unroll
    for (int t = 0; t < 2; ++t)
#pragma unroll
      for (int td = 0; td < 4; ++td)
        vf[t][td] = *(const half4v*)(Vw + ((size_t)(c * 2 + t) * 4 + l4) * 256 +
                                     (td * 16 + l15) * 4);

#pragma unroll
    for (int t = 0; t < 2; ++t)
#pragma unroll
      for (int tq = 0; tq < 2; ++tq) {
        floatx4 s = (floatx4){0.f, 0.f, 0.f, 0.f};
        s = MFMA16(kf[t][0], qf[tq][0], s);
        s = MFMA16(kf[t][1], qf[tq][1], s);
        float p0 = fexp2(s[0]), p1 = fexp2(s[1]), p2 = fexp2(s[2]), p3 = fexp2(s[3]);
        lpart[tq] += (p0 + p1) + (p2 + p3);
        H4u pa;
        pa.h2[0] = __builtin_amdgcn_cvt_pkrtz(p0, p1);
        pa.h2[1] = __builtin_amdgcn_cvt_pkrtz(p2, p3);
#pragma unroll
        for (int td = 0; td < 4; ++td)
          Oacc[tq][td] = MFMA_PV(pa.h4, vf[t][td], Oacc[tq][td]);
      }
  }

  // per-wave l reduction across l4 key-groups (each lane's exps covered its 4 keys)
  float lr[2];
#pragma unroll
  for (int tq = 0; tq < 2; ++tq) {
    float l = lpart[tq];
    l += __shfl_xor(l, 16);
    l += __shfl_xor(l, 32);
    lr[tq] = l;
  }

  // write per-wave partials to private LDS region
  u16* const Pw = lds + w * 2368;
#pragma unroll
  for (int tq = 0; tq < 2; ++tq)
#pragma unroll
    for (int td = 0; td < 4; ++td)
#pragma unroll
      for (int r = 0; r < 4; ++r)
        Pw[(size_t)(tq * 16 + l4 * 4 + r) * 72 + td * 16 + l15] = f2bf(Oacc[tq][td][r]);
  if (l4 == 0) {
    float* Lw = (float*)(Pw + 2304);
#pragma unroll
    for (int tq = 0; tq < 2; ++tq) Lw[tq * 16 + l15] = lr[tq];
  }
  __syncthreads();

  // combine: thread -> (row = tid>>2 of 64, 16 cols); sum the 2 key-half partials
  {
    int row = tid >> 2, c0 = (tid & 3) * 16;
    int qh2 = row >> 5, r32 = row & 31;
    float acc[16];
#pragma unroll
    for (int j = 0; j < 16; ++j) acc[j] = 0.f;
    float lsum = 0.f;
#pragma unroll
    for (int kv = 0; kv < 2; ++kv) {
      const u16* R = lds + (qh2 * 2 + kv) * 2368;
      lsum += ((const float*)(R + 2304))[r32];
      U128u x1, x2;
      x1.q = *(const uint4*)(R + (size_t)r32 * 72 + c0);
      x2.q = *(const uint4*)(R + (size_t)r32 * 72 + c0 + 8);
#pragma unroll
      for (int j = 0; j < 8; ++j) { acc[j] += bf2f(x1.s[j]); acc[8 + j] += bf2f(x2.s[j]); }
    }
    float inv = 1.0f / lsum;
    U128u o1, o2;
#pragma unroll
    for (int j = 0; j < 8; ++j) { o1.s[j] = f2bf(acc[j] * inv); o2.s[j] = f2bf(acc[8 + j] * inv); }
    u16* Op = Ob + (size_t)(b * 2048 + q0 + row) * 1024 + h * 64 + c0;
    *(uint4*)Op = o1.q;
    *(uint4*)(Op + 8) = o2.q;
  }
}

// ---------------- launch ----------------

extern "C" void kernel_launch(void* const* d_in, const int* in_sizes, int n_in,
                              void* d_out, int out_size, void* d_ws, size_t ws_size,
                              hipStream_t stream) {
  const float* x  = (const float*)d_in[0];
  const float* Wq = (const float*)d_in[1];
  const float* bq = (const float*)d_in[2];
  const float* Wk = (const float*)d_in[3];
  const float* bk = (const float*)d_in[4];
  const float* Wv = (const float*)d_in[5];
  const float* bv = (const float*)d_in[6];
  const float* Wo = (const float*)d_in[7];
  const float* bo = (const float*)d_in[8];

  char* p = (char*)d_ws;
  u16* Xb   = (u16*)p; p += (size_t)4096 * 1024 * 2;   // x bf16
  u16* Wt   = (u16*)p; p += (size_t)3072 * 1024 * 2;   // W_all^T bf16 [n][d]
  u16* QKV  = (u16*)p; p += (size_t)4096 * 3072 * 2;   // [token][3072] bf16 (Q pre-scaled log2e/8)
  u16* VtF  = (u16*)p; p += (size_t)32 * 128 * 1024 * 2;  // V^T f16 chunked: [bh][v][kq][d][k4]
  u16* Ob   = (u16*)p; p += (size_t)4096 * 1024 * 2;   // attention out bf16 (normalized)
  u16* Wob  = (u16*)p; p += (size_t)1024 * 1024 * 2;   // Wo bf16 [e][d]
  float* ball = (float*)p; p += 3072 * sizeof(float);

  const float qscale = 0.125f * 1.4426950408889634f;  // (1/sqrt(64)) * log2(e)

  prep_all<<<8192, 256, 0, stream>>>(x, Wo, Wq, bq, Wk, bk, Wv, bv, Xb, Wob, Wt, ball);
  gemm_bt<128, u16><<<768, 256, 0, stream>>>(Xb, Wt, ball, QKV,
                                             4096, 3072, 1024, 1024, qscale);
  transpose_v<<<dim3(32, 32), 256, 0, stream>>>(QKV, VtF);
  attn_kernel<<<1024, 256, 0, stream>>>(QKV, VtF, Ob);
  gemm_bt<64, float><<<512, 256, 0, stream>>>(Ob, Wob, bo, (float*)d_out,
                                              4096, 1024, 1024, 0, 1.0f);
}